// Round 2
// baseline (1966.087 us; speedup 1.0000x reference)
//
#include <hip/hip_runtime.h>

// ---------------- workspace layout (float offsets) ----------------
// Persistent small buffers FIRST, activations after BASE. No live overlap.
static const size_t OFF_WT0  = 0;          // 1536
static const size_t OFF_WT1  = 1536;       // 32768
static const size_t OFF_WT2  = 34304;      // 131072
static const size_t OFF_WT3  = 165376;     // 147456
static const size_t OFF_WR0A = 312832;     // 36864
static const size_t OFF_WR0B = 349696;     // 4096
static const size_t OFF_WR1A = 353792;     // 36864
static const size_t OFF_WR1B = 390656;     // 4096
static const size_t OFF_CB2  = 394752;     // 512
static const size_t OFF_PART = 395264;     // 8192
static const size_t OFF_D2   = 403456;     // 524288
static const size_t OFF_IDX  = 927744;     // 524288 -> ends 1452032
static const size_t BASE     = 1572864;
// conv0/conv1 run in two 32-batch halves so A0 is halved:
static const size_t OFF_A0H  = BASE;              // (32,32,128,128) = 16,777,216
static const size_t OFF_A1   = BASE + 16777216;   // (64,64,64,64)   = 16,777,216 -> ends 35,127,296
static const size_t OFF_A2   = BASE;              // (64,128,32,32) = 8,388,608 (A0h dead)
static const size_t OFF_A3   = BASE + 8388608;    // 8,388,608 (ends exactly at A1 start)
static const size_t OFF_H    = BASE + 16777216;   // 2,097,152 (A1 dead after conv2)
static const size_t OFF_A4   = BASE + 20447232;   // 8,388,608
static const size_t OFF_A5   = BASE + 8388608;    // over dead A3
// peak ws usage: 35,127,296 floats = 140.5 MB

// ---------------- weight transpose: w[co][ci][k] -> wt[ci*KK+k][co] ----------------
__global__ void wtrans_kernel(const float* __restrict__ w, float* __restrict__ wt,
                              int cin, int cout, int kk) {
  int i = blockIdx.x * 256 + threadIdx.x;
  int total = cin * cout * kk;
  if (i >= total) return;
  int co = i / (cin * kk);
  int r  = i - co * cin * kk;
  int ci = r / kk;
  int k  = r - ci * kk;
  wt[(size_t)(ci * kk + k) * cout + co] = w[i];
}

// ---------------- codebook squared norms ----------------
__global__ void cb_norm_kernel(const float* __restrict__ cb, float* __restrict__ cb2) {
  int k = blockIdx.x * 256 + threadIdx.x;
  if (k >= 512) return;
  const float4* p = (const float4*)(cb + (size_t)k * 128);
  float s = 0.f;
  for (int j = 0; j < 32; ++j) {
    float4 v = p[j];
    s += v.x * v.x; s += v.y * v.y; s += v.z * v.z; s += v.w * v.w;
  }
  cb2[k] = s;
}

// ---------------- generic direct conv ----------------
// block = 256 threads = 16x16 output tile, thread = 1 pixel, CO accumulators.
// weights pre-transposed so the co-loop reads consecutive floats at a
// wave-uniform address -> compiler emits scalar s_load (weights on SALU pipe).
template<int CIN, int COUT, int CO, int CC, int K, int S, int P, int HIN, int WIN,
         bool RELU_IN, bool RELU_OUT, bool ADD_RES>
__global__ __launch_bounds__(256)
void conv_kernel(const float* __restrict__ in, const float* __restrict__ wt,
                 const float* __restrict__ bias, const float* __restrict__ res,
                 float* __restrict__ out)
{
  constexpr int HOUT = (HIN + 2 * P - K) / S + 1;
  constexpr int WOUT = (WIN + 2 * P - K) / S + 1;
  constexpr int TW = WOUT / 16;
  constexpr int IT = 15 * S + K;          // input tile extent for 16 outputs
  __shared__ float in_s[CC][IT][IT + 1];

  const int tile = blockIdx.x;
  const int co0  = blockIdx.y * CO;
  const int n    = blockIdx.z;
  const int th   = (tile / TW) * 16;
  const int tw   = (tile % TW) * 16;
  const int tx   = threadIdx.x & 15;
  const int ty   = threadIdx.x >> 4;

  float acc[CO];
  #pragma unroll
  for (int i = 0; i < CO; ++i) acc[i] = 0.f;

  const int ih0 = th * S - P;
  const int iw0 = tw * S - P;
  const float* inN = in + (size_t)n * CIN * HIN * WIN;

  for (int cb0 = 0; cb0 < CIN; cb0 += CC) {
    __syncthreads();
    for (int t = threadIdx.x; t < CC * IT * IT; t += 256) {
      int ci = t / (IT * IT);
      int rm = t - ci * IT * IT;
      int r  = rm / IT;
      int c  = rm - r * IT;
      int ih = ih0 + r, iw = iw0 + c;
      float v = 0.f;
      if (ih >= 0 && ih < HIN && iw >= 0 && iw < WIN) {
        v = inN[(size_t)(cb0 + ci) * HIN * WIN + (size_t)ih * WIN + iw];
        if (RELU_IN) v = fmaxf(v, 0.f);
      }
      in_s[ci][r][c] = v;
    }
    __syncthreads();
    for (int ci = 0; ci < CC; ++ci) {
      const float* wbase = wt + ((size_t)(cb0 + ci) * K * K) * COUT + co0;
      #pragma unroll
      for (int kh = 0; kh < K; ++kh) {
        #pragma unroll
        for (int kw = 0; kw < K; ++kw) {
          float v = in_s[ci][ty * S + kh][tx * S + kw];
          const float* wrow = wbase + (size_t)(kh * K + kw) * COUT;
          #pragma unroll
          for (int co = 0; co < CO; ++co)
            acc[co] = fmaf(v, wrow[co], acc[co]);
        }
      }
    }
  }

  const int oh = th + ty, ow = tw + tx;
  float* outN = out + (size_t)n * COUT * HOUT * WOUT;
  const size_t pix = (size_t)oh * WOUT + ow;
  #pragma unroll
  for (int co = 0; co < CO; ++co) {
    float v = acc[co] + bias[co0 + co];
    if (ADD_RES)
      v += res[(size_t)n * COUT * HOUT * WOUT + (size_t)(co0 + co) * HOUT * WOUT + pix];
    if (RELU_OUT) v = fmaxf(v, 0.f);
    outN[(size_t)(co0 + co) * HOUT * WOUT + pix] = v;
  }
}

// ---------------- VQ distance: thread-per-vector, 64-codeword LDS chunks ----------------
__global__ __launch_bounds__(256)
void vq_dist_kernel(const float* __restrict__ enc, const float* __restrict__ cb,
                    const float* __restrict__ cb2, float* __restrict__ d2o,
                    int* __restrict__ io)
{
  __shared__ float cb_s[64 * 128];
  __shared__ float cb2_s[64];
  const int chunk = blockIdx.y;                       // 0..7, 64 codewords each
  const int vec   = blockIdx.x * 256 + threadIdx.x;   // 0..65535

  for (int t = threadIdx.x; t < 64 * 128 / 4; t += 256)
    ((float4*)cb_s)[t] = ((const float4*)(cb + (size_t)chunk * 64 * 128))[t];
  if (threadIdx.x < 64) cb2_s[threadIdx.x] = cb2[chunk * 64 + threadIdx.x];
  __syncthreads();

  float4 f[32];
  float f2 = 0.f;
  const float4* fp = (const float4*)(enc + (size_t)vec * 128);
  #pragma unroll
  for (int j = 0; j < 32; ++j) {
    float4 v = fp[j];
    v.x = fmaxf(v.x, 0.f); v.y = fmaxf(v.y, 0.f);
    v.z = fmaxf(v.z, 0.f); v.w = fmaxf(v.w, 0.f);
    f[j] = v;
    f2 += v.x * v.x; f2 += v.y * v.y; f2 += v.z * v.z; f2 += v.w * v.w;
  }

  float best = 3.0e38f;
  int bi = 0;
  for (int k = 0; k < 64; ++k) {
    const float4* ck = (const float4*)(cb_s + k * 128);
    float d0 = 0.f, d1 = 0.f, d2 = 0.f, d3 = 0.f;
    #pragma unroll
    for (int j = 0; j < 32; ++j) {
      float4 c4 = ck[j];
      d0 = fmaf(f[j].x, c4.x, d0);
      d1 = fmaf(f[j].y, c4.y, d1);
      d2 = fmaf(f[j].z, c4.z, d2);
      d3 = fmaf(f[j].w, c4.w, d3);
    }
    float dot = (d0 + d1) + (d2 + d3);
    float dist = fmaf(-2.f, dot, f2) + cb2_s[k];
    if (dist < best) { best = dist; bi = k; }   // strict < : first-occurrence argmin
  }
  d2o[(size_t)chunk * 65536 + vec] = best;
  io [(size_t)chunk * 65536 + vec] = chunk * 64 + bi;
}

// ---------------- gather codeword + commit partials ----------------
__global__ __launch_bounds__(256)
void vq_gather_kernel(const float* __restrict__ enc, const float* __restrict__ cb,
                      const float* __restrict__ d2m, const int* __restrict__ idxs,
                      float* __restrict__ out, float* __restrict__ partial)
{
  const int t   = threadIdx.x;
  const int vec = blockIdx.x * 8 + (t >> 5);
  const int j   = t & 31;

  float best = d2m[vec];
  int bi = idxs[vec];
  #pragma unroll
  for (int c = 1; c < 8; ++c) {                 // ascending chunk scan keeps lowest idx on tie
    float d = d2m[(size_t)c * 65536 + vec];
    int  i2 = idxs[(size_t)c * 65536 + vec];
    if (d < best) { best = d; bi = i2; }
  }

  float4 q = ((const float4*)(cb + (size_t)bi * 128))[j];
  float4 f = ((const float4*)(enc + (size_t)vec * 128))[j];
  f.x = fmaxf(f.x, 0.f); f.y = fmaxf(f.y, 0.f);
  f.z = fmaxf(f.z, 0.f); f.w = fmaxf(f.w, 0.f);
  ((float4*)out)[(size_t)vec * 32 + j] = q;

  float dx = q.x - f.x, dy = q.y - f.y, dz = q.z - f.z, dw = q.w - f.w;
  float c = dx * dx + dy * dy + dz * dz + dw * dw;
  #pragma unroll
  for (int off = 32; off > 0; off >>= 1) c += __shfl_down(c, off, 64);
  __shared__ float ls[4];
  if ((t & 63) == 0) ls[t >> 6] = c;
  __syncthreads();
  if (t == 0) partial[blockIdx.x] = (ls[0] + ls[1]) + (ls[2] + ls[3]);
}

__global__ void commit_finalize_kernel(const float* __restrict__ part,
                                       float* __restrict__ outc)
{
  __shared__ double sd[256];
  double s = 0.0;
  for (int i = threadIdx.x; i < 8192; i += 256) s += (double)part[i];
  sd[threadIdx.x] = s;
  __syncthreads();
  for (int off = 128; off > 0; off >>= 1) {
    if (threadIdx.x < off) sd[threadIdx.x] += sd[threadIdx.x + off];
    __syncthreads();
  }
  if (threadIdx.x == 0) *outc = (float)(sd[0] / 8388608.0);
}

// ---------------- launch ----------------
extern "C" void kernel_launch(void* const* d_in, const int* in_sizes, int n_in,
                              void* d_out, int out_size, void* d_ws, size_t ws_size,
                              hipStream_t stream)
{
  (void)in_sizes; (void)n_in; (void)out_size; (void)ws_size;
  const float* x    = (const float*)d_in[0];
  const float* c0_w = (const float*)d_in[1];
  const float* c0_b = (const float*)d_in[2];
  const float* c1_w = (const float*)d_in[3];
  const float* c1_b = (const float*)d_in[4];
  const float* c2_w = (const float*)d_in[5];
  const float* c2_b = (const float*)d_in[6];
  const float* c3_w = (const float*)d_in[7];
  const float* c3_b = (const float*)d_in[8];
  const float* r0a_w = (const float*)d_in[9];
  const float* r0a_b = (const float*)d_in[10];
  const float* r0b_w = (const float*)d_in[11];
  const float* r0b_b = (const float*)d_in[12];
  const float* r1a_w = (const float*)d_in[13];
  const float* r1a_b = (const float*)d_in[14];
  const float* r1b_w = (const float*)d_in[15];
  const float* r1b_b = (const float*)d_in[16];
  const float* cbk   = (const float*)d_in[17];

  float* out = (float*)d_out;
  float* wsf = (float*)d_ws;

  float* WT0 = wsf + OFF_WT0;
  float* WT1 = wsf + OFF_WT1;
  float* WT2 = wsf + OFF_WT2;
  float* WT3 = wsf + OFF_WT3;
  float* WR0A = wsf + OFF_WR0A;
  float* WR0B = wsf + OFF_WR0B;
  float* WR1A = wsf + OFF_WR1A;
  float* WR1B = wsf + OFF_WR1B;
  float* CB2 = wsf + OFF_CB2;
  float* PT  = wsf + OFF_PART;
  float* D2  = wsf + OFF_D2;
  int*   IX  = (int*)(wsf + OFF_IDX);
  float* A0H = wsf + OFF_A0H;
  float* A1  = wsf + OFF_A1;
  float* A2  = wsf + OFF_A2;
  float* A3  = wsf + OFF_A3;
  float* H   = wsf + OFF_H;
  float* A4  = wsf + OFF_A4;
  float* A5  = wsf + OFF_A5;

  // weight transposes (tiny)
  wtrans_kernel<<<6,   256, 0, stream>>>(c0_w, WT0, 3, 32, 16);
  wtrans_kernel<<<128, 256, 0, stream>>>(c1_w, WT1, 32, 64, 16);
  wtrans_kernel<<<512, 256, 0, stream>>>(c2_w, WT2, 64, 128, 16);
  wtrans_kernel<<<576, 256, 0, stream>>>(c3_w, WT3, 128, 128, 9);
  wtrans_kernel<<<144, 256, 0, stream>>>(r0a_w, WR0A, 128, 32, 9);
  wtrans_kernel<<<16,  256, 0, stream>>>(r0b_w, WR0B, 32, 128, 1);
  wtrans_kernel<<<144, 256, 0, stream>>>(r1a_w, WR1A, 128, 32, 9);
  wtrans_kernel<<<16,  256, 0, stream>>>(r1b_w, WR1B, 32, 128, 1);
  cb_norm_kernel<<<2, 256, 0, stream>>>(cbk, CB2);

  // conv0 + conv1 in two 32-batch halves (batches independent) to halve A0
  for (int h = 0; h < 2; ++h) {
    const float* xh = x + (size_t)h * 32 * 3 * 256 * 256;
    float* a1h = A1 + (size_t)h * 32 * 64 * 64 * 64;
    conv_kernel<3, 32, 32, 3, 4, 2, 1, 256, 256, false, true,  false>
        <<<dim3(64, 1, 32), 256, 0, stream>>>(xh, WT0, c0_b, nullptr, A0H);
    conv_kernel<32, 64, 64, 8, 4, 2, 1, 128, 128, false, true,  false>
        <<<dim3(16, 1, 32), 256, 0, stream>>>(A0H, WT1, c1_b, nullptr, a1h);
  }
  conv_kernel<64, 128, 64, 8, 4, 2, 1, 64, 64,  false, true,  false>
      <<<dim3(4, 2, 64), 256, 0, stream>>>(A1, WT2, c2_b, nullptr, A2);
  conv_kernel<128, 128, 64, 8, 3, 1, 1, 32, 32, false, false, false>
      <<<dim3(4, 2, 64), 256, 0, stream>>>(A2, WT3, c3_b, nullptr, A3);
  // resblock 0
  conv_kernel<128, 32, 16, 8, 3, 1, 1, 32, 32,  true,  true,  false>
      <<<dim3(4, 2, 64), 256, 0, stream>>>(A3, WR0A, r0a_b, nullptr, H);
  conv_kernel<32, 128, 64, 8, 1, 1, 0, 32, 32,  false, false, true>
      <<<dim3(4, 2, 64), 256, 0, stream>>>(H, WR0B, r0b_b, A3, A4);
  // resblock 1
  conv_kernel<128, 32, 16, 8, 3, 1, 1, 32, 32,  true,  true,  false>
      <<<dim3(4, 2, 64), 256, 0, stream>>>(A4, WR1A, r1a_b, nullptr, H);
  conv_kernel<32, 128, 64, 8, 1, 1, 0, 32, 32,  false, false, true>
      <<<dim3(4, 2, 64), 256, 0, stream>>>(H, WR1B, r1b_b, A4, A5);

  // VQ (final relu applied on load inside both kernels)
  vq_dist_kernel<<<dim3(256, 8), 256, 0, stream>>>(A5, cbk, CB2, D2, IX);
  vq_gather_kernel<<<8192, 256, 0, stream>>>(A5, cbk, D2, IX, out, PT);
  commit_finalize_kernel<<<1, 256, 0, stream>>>(PT, out + 8388608);
}